// Round 5
// baseline (38.215 us; speedup 1.0000x reference)
//
#include <hip/hip_runtime.h>

// PhysConstrainedLES: fused divergence + pressure-Poisson RHS stencils.
// uPred: [B,2,H,W] f32, pPred: [B,1,H,W] f32
// out:  div [B,510,512] then pstar [B,510,510], concatenated flat, f32.
//
// One row per WAVE: lane l owns cols 8l..8l+7 (2x float4 per row per array).
// All halo columns via 13 wave shuffles; edge clamps resolve to the lane's
// OWN registers (replicate-pad for free, no scalar edge loads).
// Outputs stored non-temporally (never re-read) to keep inputs L3-resident.
// Bijective XCD swizzle: consecutive row-pairs of one batch share an XCD L2.

#define BN 32
#define HH 512
#define WW 512
#define OH 510
#define OW2 510
#define NBLK (OH * BN / 2)   // 8160 blocks x 2 waves, divisible by 8

typedef float f32x4 __attribute__((ext_vector_type(4)));
typedef float f32x2 __attribute__((ext_vector_type(2)));

__device__ __forceinline__ float clip1(float x) {
    return fminf(fmaxf(x, -1.0f), 1.0f);
}

__global__ __launch_bounds__(128) void pcles_kernel(
    const float* __restrict__ u_,   // [B,2,H,W]
    const float* __restrict__ p_,   // [B,1,H,W]
    float* __restrict__ div_out,    // [B,510,512]
    float* __restrict__ ps_out)     // [B,510,510]
{
    const int bid = blockIdx.x;
    const int nb  = (bid & 7) * (NBLK / 8) + (bid >> 3);   // bijective XCD swizzle
    const int b     = nb / (OH / 2);
    const int hpair = nb % (OH / 2);
    const int wave  = (int)threadIdx.x >> 6;
    const int lane  = (int)threadIdx.x & 63;
    const int h  = hpair * 2 + wave;     // 0..509 (rows h, h+1, h+2 read)
    const int wc = lane * 8;             // 0..504

    const float* ub = u_ + (size_t)b * 2 * HH * WW;
    const float* vb = ub + HH * WW;
    const float* pb = p_ + (size_t)b * HH * WW;
    const float* ur = ub + h * WW + wc;
    const float* vr = vb + h * WW + wc;
    const float* pr = pb + h * WW + wc;

    // 18 independent 16B loads
    const float4 ua0 = *(const float4*)(ur);                // row h,   cols wc..wc+3
    const float4 ua1 = *(const float4*)(ur + 4);            //          cols wc+4..wc+7
    const float4 ub0 = *(const float4*)(ur + WW);           // row h+1
    const float4 ub1 = *(const float4*)(ur + WW + 4);
    const float4 uc0 = *(const float4*)(ur + 2 * WW);       // row h+2
    const float4 uc1 = *(const float4*)(ur + 2 * WW + 4);
    const float4 va0 = *(const float4*)(vr);
    const float4 va1 = *(const float4*)(vr + 4);
    const float4 vb0 = *(const float4*)(vr + WW);
    const float4 vb1 = *(const float4*)(vr + WW + 4);
    const float4 vc0 = *(const float4*)(vr + 2 * WW);
    const float4 vc1 = *(const float4*)(vr + 2 * WW + 4);
    const float4 pa0 = *(const float4*)(pr);
    const float4 pa1 = *(const float4*)(pr + 4);
    const float4 pb0 = *(const float4*)(pr + WW);
    const float4 pb1 = *(const float4*)(pr + WW + 4);
    const float4 pc0 = *(const float4*)(pr + 2 * WW);
    const float4 pc1 = *(const float4*)(pr + 2 * WW + 4);

    // halos via shuffles; wave edges clamp to OWN registers (replicate pad)
    float uLm  = __shfl_up(ub1.w, 1);     // row h+1, col wc-1
    float uRa  = __shfl_down(ua0.x, 1);   // row h,   col wc+8
    float uRb  = __shfl_down(ub0.x, 1);   // row h+1, col wc+8
    float uRb2 = __shfl_down(ub0.y, 1);   // row h+1, col wc+9
    float uRc  = __shfl_down(uc0.x, 1);   // row h+2, col wc+8
    float vRa  = __shfl_down(va0.x, 1);
    float vRb  = __shfl_down(vb0.x, 1);
    float vRb2 = __shfl_down(vb0.y, 1);
    float vRc  = __shfl_down(vc0.x, 1);
    float pRa  = __shfl_down(pa0.x, 1);
    float pRb  = __shfl_down(pb0.x, 1);
    float pRb2 = __shfl_down(pb0.y, 1);
    float pRc  = __shfl_down(pc0.x, 1);
    if (lane == 0) uLm = ub0.x;                       // clamp col -1 -> 0
    if (lane == 63) {                                 // clamp cols 512,513 -> 511
        uRa = ua1.w; uRb = ub1.w; uRb2 = ub1.w; uRc = uc1.w;
        vRa = va1.w; vRb = vb1.w; vRb2 = vb1.w; vRc = vc1.w;
        pRa = pa1.w; pRb = pb1.w; pRb2 = pb1.w; pRc = pc1.w;
    }

    // constant-indexed windows (unrolled -> pure VGPRs)
    const float u1w[11] = {uLm, ub0.x, ub0.y, ub0.z, ub0.w, ub1.x, ub1.y, ub1.z, ub1.w, uRb, uRb2}; // cols wc-1..wc+9
    const float u0w[9]  = {ua0.x, ua0.y, ua0.z, ua0.w, ua1.x, ua1.y, ua1.z, ua1.w, uRa};            // cols wc..wc+8
    const float u2w[9]  = {uc0.x, uc0.y, uc0.z, uc0.w, uc1.x, uc1.y, uc1.z, uc1.w, uRc};
    const float v1w[10] = {vb0.x, vb0.y, vb0.z, vb0.w, vb1.x, vb1.y, vb1.z, vb1.w, vRb, vRb2};      // cols wc..wc+9
    const float v0w[9]  = {va0.x, va0.y, va0.z, va0.w, va1.x, va1.y, va1.z, va1.w, vRa};
    const float v2w[9]  = {vc0.x, vc0.y, vc0.z, vc0.w, vc1.x, vc1.y, vc1.z, vc1.w, vRc};
    const float p1w[10] = {pb0.x, pb0.y, pb0.z, pb0.w, pb1.x, pb1.y, pb1.z, pb1.w, pRb, pRb2};
    const float p0w[9]  = {pa0.x, pa0.y, pa0.z, pa0.w, pa1.x, pa1.y, pa1.z, pa1.w, pRa};
    const float p2w[9]  = {pc0.x, pc0.y, pc0.z, pc0.w, pc1.x, pc1.y, pc1.z, pc1.w, pRc};

    float dv[8], ps[8];
    #pragma unroll
    for (int j = 0; j < 8; ++j) {
        const float dudx = (u1w[j + 2] - u1w[j]) * 50.0f;
        const float dvdy = (v2w[j] - v0w[j]) * 50.0f;
        dv[j] = clip1(0.01f * (dvdy + dudx));

        const float pc  = p1w[j + 1];
        const float ddp = (p1w[j] - 2.0f * pc + p1w[j + 2]) * 1.0e4f
                        + (p0w[j + 1] - 2.0f * pc + p2w[j + 1]) * 1.0e4f;
        const float ux = (u1w[j + 3] - u1w[j + 1]) * 50.0f;
        const float uy = (u2w[j + 1] - u0w[j + 1]) * 50.0f;
        const float vx = (v1w[j + 2] - v1w[j]) * 50.0f;
        const float vy = (v2w[j + 1] - v0w[j + 1]) * 50.0f;
        const float rhs = ux * ux + 2.0f * uy * vx + vy * vy;
        ps[j] = clip1(1.0e-4f * (ddp + rhs));
    }

    // non-temporal stores (ext_vector types -- the builtin rejects HIP_vector_type)
    float* dr = div_out + ((size_t)b * OH + h) * WW + wc;   // 32B-aligned
    f32x4 d0 = {dv[0], dv[1], dv[2], dv[3]};
    f32x4 d1 = {dv[4], dv[5], dv[6], dv[7]};
    __builtin_nontemporal_store(d0, (f32x4*)dr);
    __builtin_nontemporal_store(d1, (f32x4*)(dr + 4));

    float* pw = ps_out + ((size_t)b * OH + h) * OW2 + wc;   // 8B-aligned only
    #pragma unroll
    for (int k = 0; k < 4; ++k) {
        if (wc + 2 * k < OW2) {  // lane 63 covers cols 504..509 only
            f32x2 t = {ps[2 * k], ps[2 * k + 1]};
            __builtin_nontemporal_store(t, (f32x2*)(pw + 2 * k));
        }
    }
}

extern "C" void kernel_launch(void* const* d_in, const int* in_sizes, int n_in,
                              void* d_out, int out_size, void* d_ws, size_t ws_size,
                              hipStream_t stream) {
    const float* uPred = (const float*)d_in[0];
    const float* pPred = (const float*)d_in[1];
    float* div_out = (float*)d_out;
    float* ps_out  = div_out + (size_t)BN * OH * WW;

    pcles_kernel<<<dim3(NBLK), dim3(128), 0, stream>>>(uPred, pPred, div_out, ps_out);
}

// Round 6
// 32.137 us; speedup vs baseline: 1.1891x; 1.1891x over previous
//
#include <hip/hip_runtime.h>

// PhysConstrainedLES: fused divergence + pressure-Poisson RHS stencils.
// uPred: [B,2,H,W] f32, pPred: [B,1,H,W] f32
// out:  div [B,510,512] then pstar [B,510,510], concatenated flat, f32.
//
// One row per WAVE: lane l owns cols 8l..8l+7 (2x float4 per row per array).
// All halo columns via 13 wave shuffles; edge clamps resolve to the lane's
// OWN registers (replicate-pad for free, no scalar edge loads).
// Plain stores (R5 lesson: non-temporal 8B stores doubled pstar HBM write
// traffic, 65->104 MB, and gave zero fetch benefit -- let L2 write-combine).
// Bijective XCD swizzle: consecutive row-pairs of one batch share an XCD L2.

#define BN 32
#define HH 512
#define WW 512
#define OH 510
#define OW2 510
#define NBLK (OH * BN / 2)   // 8160 blocks x 2 waves, divisible by 8

__device__ __forceinline__ float clip1(float x) {
    return fminf(fmaxf(x, -1.0f), 1.0f);
}

__global__ __launch_bounds__(128) void pcles_kernel(
    const float* __restrict__ u_,   // [B,2,H,W]
    const float* __restrict__ p_,   // [B,1,H,W]
    float* __restrict__ div_out,    // [B,510,512]
    float* __restrict__ ps_out)     // [B,510,510]
{
    const int bid = blockIdx.x;
    const int nb  = (bid & 7) * (NBLK / 8) + (bid >> 3);   // bijective XCD swizzle
    const int b     = nb / (OH / 2);
    const int hpair = nb % (OH / 2);
    const int wave  = (int)threadIdx.x >> 6;
    const int lane  = (int)threadIdx.x & 63;
    const int h  = hpair * 2 + wave;     // 0..509 (rows h, h+1, h+2 read)
    const int wc = lane * 8;             // 0..504

    const float* ub = u_ + (size_t)b * 2 * HH * WW;
    const float* vb = ub + HH * WW;
    const float* pb = p_ + (size_t)b * HH * WW;
    const float* ur = ub + h * WW + wc;
    const float* vr = vb + h * WW + wc;
    const float* pr = pb + h * WW + wc;

    // 18 independent 16B loads
    const float4 ua0 = *(const float4*)(ur);                // row h,   cols wc..wc+3
    const float4 ua1 = *(const float4*)(ur + 4);            //          cols wc+4..wc+7
    const float4 ub0 = *(const float4*)(ur + WW);           // row h+1
    const float4 ub1 = *(const float4*)(ur + WW + 4);
    const float4 uc0 = *(const float4*)(ur + 2 * WW);       // row h+2
    const float4 uc1 = *(const float4*)(ur + 2 * WW + 4);
    const float4 va0 = *(const float4*)(vr);
    const float4 va1 = *(const float4*)(vr + 4);
    const float4 vb0 = *(const float4*)(vr + WW);
    const float4 vb1 = *(const float4*)(vr + WW + 4);
    const float4 vc0 = *(const float4*)(vr + 2 * WW);
    const float4 vc1 = *(const float4*)(vr + 2 * WW + 4);
    const float4 pa0 = *(const float4*)(pr);
    const float4 pa1 = *(const float4*)(pr + 4);
    const float4 pb0 = *(const float4*)(pr + WW);
    const float4 pb1 = *(const float4*)(pr + WW + 4);
    const float4 pc0 = *(const float4*)(pr + 2 * WW);
    const float4 pc1 = *(const float4*)(pr + 2 * WW + 4);

    // halos via shuffles; wave edges clamp to OWN registers (replicate pad)
    float uLm  = __shfl_up(ub1.w, 1);     // row h+1, col wc-1
    float uRa  = __shfl_down(ua0.x, 1);   // row h,   col wc+8
    float uRb  = __shfl_down(ub0.x, 1);   // row h+1, col wc+8
    float uRb2 = __shfl_down(ub0.y, 1);   // row h+1, col wc+9
    float uRc  = __shfl_down(uc0.x, 1);   // row h+2, col wc+8
    float vRa  = __shfl_down(va0.x, 1);
    float vRb  = __shfl_down(vb0.x, 1);
    float vRb2 = __shfl_down(vb0.y, 1);
    float vRc  = __shfl_down(vc0.x, 1);
    float pRa  = __shfl_down(pa0.x, 1);
    float pRb  = __shfl_down(pb0.x, 1);
    float pRb2 = __shfl_down(pb0.y, 1);
    float pRc  = __shfl_down(pc0.x, 1);
    if (lane == 0) uLm = ub0.x;                       // clamp col -1 -> 0
    if (lane == 63) {                                 // clamp cols 512,513 -> 511
        uRa = ua1.w; uRb = ub1.w; uRb2 = ub1.w; uRc = uc1.w;
        vRa = va1.w; vRb = vb1.w; vRb2 = vb1.w; vRc = vc1.w;
        pRa = pa1.w; pRb = pb1.w; pRb2 = pb1.w; pRc = pc1.w;
    }

    // constant-indexed windows (unrolled -> pure VGPRs)
    const float u1w[11] = {uLm, ub0.x, ub0.y, ub0.z, ub0.w, ub1.x, ub1.y, ub1.z, ub1.w, uRb, uRb2}; // cols wc-1..wc+9
    const float u0w[9]  = {ua0.x, ua0.y, ua0.z, ua0.w, ua1.x, ua1.y, ua1.z, ua1.w, uRa};            // cols wc..wc+8
    const float u2w[9]  = {uc0.x, uc0.y, uc0.z, uc0.w, uc1.x, uc1.y, uc1.z, uc1.w, uRc};
    const float v1w[10] = {vb0.x, vb0.y, vb0.z, vb0.w, vb1.x, vb1.y, vb1.z, vb1.w, vRb, vRb2};      // cols wc..wc+9
    const float v0w[9]  = {va0.x, va0.y, va0.z, va0.w, va1.x, va1.y, va1.z, va1.w, vRa};
    const float v2w[9]  = {vc0.x, vc0.y, vc0.z, vc0.w, vc1.x, vc1.y, vc1.z, vc1.w, vRc};
    const float p1w[10] = {pb0.x, pb0.y, pb0.z, pb0.w, pb1.x, pb1.y, pb1.z, pb1.w, pRb, pRb2};
    const float p0w[9]  = {pa0.x, pa0.y, pa0.z, pa0.w, pa1.x, pa1.y, pa1.z, pa1.w, pRa};
    const float p2w[9]  = {pc0.x, pc0.y, pc0.z, pc0.w, pc1.x, pc1.y, pc1.z, pc1.w, pRc};

    float dv[8], ps[8];
    #pragma unroll
    for (int j = 0; j < 8; ++j) {
        const float dudx = (u1w[j + 2] - u1w[j]) * 50.0f;
        const float dvdy = (v2w[j] - v0w[j]) * 50.0f;
        dv[j] = clip1(0.01f * (dvdy + dudx));

        const float pc  = p1w[j + 1];
        const float ddp = (p1w[j] - 2.0f * pc + p1w[j + 2]) * 1.0e4f
                        + (p0w[j + 1] - 2.0f * pc + p2w[j + 1]) * 1.0e4f;
        const float ux = (u1w[j + 3] - u1w[j + 1]) * 50.0f;
        const float uy = (u2w[j + 1] - u0w[j + 1]) * 50.0f;
        const float vx = (v1w[j + 2] - v1w[j]) * 50.0f;
        const float vy = (v2w[j + 1] - v0w[j + 1]) * 50.0f;
        const float rhs = ux * ux + 2.0f * uy * vx + vy * vy;
        ps[j] = clip1(1.0e-4f * (ddp + rhs));
    }

    // plain stores: L2 write-combines (R5: NT here doubled pstar HBM writes)
    float* dr = div_out + ((size_t)b * OH + h) * WW + wc;   // 32B-aligned
    *(float4*)dr       = make_float4(dv[0], dv[1], dv[2], dv[3]);
    *(float4*)(dr + 4) = make_float4(dv[4], dv[5], dv[6], dv[7]);

    float* pw = ps_out + ((size_t)b * OH + h) * OW2 + wc;   // 8B-aligned only
    #pragma unroll
    for (int k = 0; k < 4; ++k) {
        if (wc + 2 * k < OW2)   // lane 63 covers cols 504..509 only
            *(float2*)(pw + 2 * k) = make_float2(ps[2 * k], ps[2 * k + 1]);
    }
}

extern "C" void kernel_launch(void* const* d_in, const int* in_sizes, int n_in,
                              void* d_out, int out_size, void* d_ws, size_t ws_size,
                              hipStream_t stream) {
    const float* uPred = (const float*)d_in[0];
    const float* pPred = (const float*)d_in[1];
    float* div_out = (float*)d_out;
    float* ps_out  = div_out + (size_t)BN * OH * WW;

    pcles_kernel<<<dim3(NBLK), dim3(128), 0, stream>>>(uPred, pPred, div_out, ps_out);
}

// Round 7
// 29.476 us; speedup vs baseline: 1.2965x; 1.0903x over previous
//
#include <hip/hip_runtime.h>

// PhysConstrainedLES: fused divergence + pressure-Poisson RHS stencils.
// uPred: [B,2,H,W] f32, pPred: [B,1,H,W] f32
// out:  div [B,510,512] then pstar [B,510,510], concatenated flat, f32.
//
// R3 structure (best so far, 29.75us): one row per block, 128 thr x 4 cols,
// 32640 waves, halos via intra-wave shuffles + lane-edge scalar loads.
// R7 change: div stores are NON-TEMPORAL. In this layout each div store
// instruction is lane-contiguous (64 lanes x 16B = 1KB full lines), so NT
// write-combines correctly (R5's 2x write blowup was half-line NT stores).
// pstar rows are 2040B (8B-aligned) -> keep plain stores there.
// Goal: stop div writes from allocating in L3 so the 96MB input set stays
// L3-resident across replays (96 + 32 < 256MB) -> FETCH_SIZE drops.

#define BN 32
#define HH 512
#define WW 512
#define OH 510
#define OW2 510
#define NBLK (OH * BN)   // 16320, divisible by 8

typedef float f32x4 __attribute__((ext_vector_type(4)));

__device__ __forceinline__ float clip1(float x) {
    return fminf(fmaxf(x, -1.0f), 1.0f);
}

__global__ __launch_bounds__(128) void pcles_kernel(
    const float* __restrict__ u_,   // [B,2,H,W]
    const float* __restrict__ p_,   // [B,1,H,W]
    float* __restrict__ div_out,    // [B,510,512]
    float* __restrict__ ps_out)     // [B,510,510]
{
    // bijective XCD swizzle: XCD k gets nb in [k*2040, (k+1)*2040) ->
    // consecutive h within a batch on one XCD -> vertical reuse in its L2.
    const int bid = blockIdx.x;
    const int nb  = (bid & 7) * (NBLK / 8) + (bid >> 3);
    const int b   = nb / OH;
    const int h   = nb % OH;

    const int tid  = (int)threadIdx.x;
    const int wc   = tid * 4;        // 0..508
    const int lane = tid & 63;

    const float* ub = u_ + (size_t)b * 2 * HH * WW;
    const float* vb = ub + HH * WW;
    const float* pb = p_ + (size_t)b * HH * WW;

    const float* ur0 = ub + h * WW;          // rows h, h+1, h+2
    const float* vr0 = vb + h * WW;
    const float* pr0 = pb + h * WW;

    // 9 independent vector loads (MLP)
    const float4 tu0 = *(const float4*)(ur0 + wc);
    const float4 tu1 = *(const float4*)(ur0 + WW + wc);
    const float4 tu2 = *(const float4*)(ur0 + 2 * WW + wc);
    const float4 tv0 = *(const float4*)(vr0 + wc);
    const float4 tv1 = *(const float4*)(vr0 + WW + wc);
    const float4 tv2 = *(const float4*)(vr0 + 2 * WW + wc);
    const float4 tp0 = *(const float4*)(pr0 + wc);
    const float4 tp1 = *(const float4*)(pr0 + WW + wc);
    const float4 tp2 = *(const float4*)(pr0 + 2 * WW + wc);

    // halo columns via shuffles (wave-internal); fix wave-edge lanes below
    float uL1   = __shfl_up(tu1.w, 1);     // col wc-1, row h+1
    float uR1_0 = __shfl_down(tu0.x, 1);   // col wc+4, row h
    float uR1_1 = __shfl_down(tu1.x, 1);   // col wc+4, row h+1
    float uR1_2 = __shfl_down(tu2.x, 1);   // col wc+4, row h+2
    float uR2_1 = __shfl_down(tu1.y, 1);   // col wc+5, row h+1
    float vR1_0 = __shfl_down(tv0.x, 1);
    float vR1_1 = __shfl_down(tv1.x, 1);
    float vR1_2 = __shfl_down(tv2.x, 1);
    float vR2_1 = __shfl_down(tv1.y, 1);
    float pR1_0 = __shfl_down(tp0.x, 1);
    float pR1_1 = __shfl_down(tp1.x, 1);
    float pR1_2 = __shfl_down(tp2.x, 1);
    float pR2_1 = __shfl_down(tp1.y, 1);

    const int cL = (wc > 0) ? wc - 1 : 0;              // replicate-pad clamp
    const int c4 = (wc + 4 < WW) ? wc + 4 : WW - 1;
    const int c5 = (wc + 5 < WW) ? wc + 5 : WW - 1;
    if (lane == 0)  uL1 = ur0[WW + cL];
    if (lane == 63) {
        uR1_0 = ur0[c4];          uR1_1 = ur0[WW + c4];  uR1_2 = ur0[2 * WW + c4];
        uR2_1 = ur0[WW + c5];
        vR1_0 = vr0[c4];          vR1_1 = vr0[WW + c4];  vR1_2 = vr0[2 * WW + c4];
        vR2_1 = vr0[WW + c5];
        pR1_0 = pr0[c4];          pR1_1 = pr0[WW + c4];  pR1_2 = pr0[2 * WW + c4];
        pR2_1 = pr0[WW + c5];
    }

    // register windows (constant-indexed -> stay in VGPRs)
    const float u0[5] = {tu0.x, tu0.y, tu0.z, tu0.w, uR1_0};             // cols wc..wc+4
    const float u1[7] = {uL1, tu1.x, tu1.y, tu1.z, tu1.w, uR1_1, uR2_1}; // cols wc-1..wc+5
    const float u2[5] = {tu2.x, tu2.y, tu2.z, tu2.w, uR1_2};
    const float v0[5] = {tv0.x, tv0.y, tv0.z, tv0.w, vR1_0};
    const float v1[6] = {tv1.x, tv1.y, tv1.z, tv1.w, vR1_1, vR2_1};     // cols wc..wc+5
    const float v2[5] = {tv2.x, tv2.y, tv2.z, tv2.w, vR1_2};
    const float p0[5] = {tp0.x, tp0.y, tp0.z, tp0.w, pR1_0};
    const float p1[6] = {tp1.x, tp1.y, tp1.z, tp1.w, pR1_1, pR2_1};
    const float p2[5] = {tp2.x, tp2.y, tp2.z, tp2.w, pR1_2};

    float dv[4], ps[4];
    #pragma unroll
    for (int j = 0; j < 4; ++j) {
        const float dudx = (u1[j + 2] - u1[j]) * 50.0f;
        const float dvdy = (v2[j] - v0[j]) * 50.0f;
        dv[j] = clip1(0.01f * (dvdy + dudx));

        const float pc  = p1[j + 1];
        const float ddp = (p1[j] - 2.0f * pc + p1[j + 2]) * 1.0e4f
                        + (p0[j + 1] - 2.0f * pc + p2[j + 1]) * 1.0e4f;
        const float ux = (u1[j + 3] - u1[j + 1]) * 50.0f;
        const float uy = (u2[j + 1] - u0[j + 1]) * 50.0f;
        const float vx = (v1[j + 2] - v1[j]) * 50.0f;
        const float vy = (v2[j + 1] - v0[j + 1]) * 50.0f;
        const float rhs = ux * ux + 2.0f * uy * vx + vy * vy;
        ps[j] = clip1(1.0e-4f * (ddp + rhs));
    }

    // div: non-temporal full-line store (lane-contiguous 1KB per wave instr)
    float* dr = div_out + ((size_t)b * OH + h) * WW + wc;
    f32x4 dvv = {dv[0], dv[1], dv[2], dv[3]};
    __builtin_nontemporal_store(dvv, (f32x4*)dr);

    // pstar: plain stores (rows 8B-aligned; let L2 write-combine)
    float* pr = ps_out + ((size_t)b * OH + h) * OW2 + wc;
    *(float2*)pr = make_float2(ps[0], ps[1]);
    if (wc + 2 < OW2) *(float2*)(pr + 2) = make_float2(ps[2], ps[3]);
}

extern "C" void kernel_launch(void* const* d_in, const int* in_sizes, int n_in,
                              void* d_out, int out_size, void* d_ws, size_t ws_size,
                              hipStream_t stream) {
    const float* uPred = (const float*)d_in[0];
    const float* pPred = (const float*)d_in[1];
    float* div_out = (float*)d_out;
    float* ps_out  = div_out + (size_t)BN * OH * WW;

    pcles_kernel<<<dim3(NBLK), dim3(128), 0, stream>>>(uPred, pPred, div_out, ps_out);
}